// Round 21
// baseline (93.563 us; speedup 1.0000x reference)
//
#include <hip/hip_runtime.h>
#include <hip/hip_bf16.h>

#define B_ 2
#define T_ 2048
#define C_ 1024
#define NH 16
#define NKV 4
#define HD 64
#define NQKV 1536
#define KVB 64

typedef __attribute__((ext_vector_type(4))) float f32x4;
typedef __attribute__((ext_vector_type(8))) short bf16x8;
typedef __attribute__((ext_vector_type(4))) short bf16x4;

__device__ __forceinline__ unsigned short f2bf(float f) {
  __hip_bfloat16 h = __float2bfloat16(f);
  unsigned short u;
  __builtin_memcpy(&u, &h, 2);
  return u;
}

__device__ __forceinline__ void gload16(const void* g, void* l) {
  __builtin_amdgcn_global_load_lds(
      (const __attribute__((address_space(1))) void*)g,
      (__attribute__((address_space(3))) void*)l, 16, 0, 0);
}

__device__ __forceinline__ unsigned cvtpk(float lo, float hi_) {
  unsigned w;
  asm("v_cvt_pk_bf16_f32 %0, %1, %2" : "=v"(w) : "v"(lo), "v"(hi_));
  return w;
}

// ---------------- fused f32 -> bf16 convert for all 5 tensors (R17-proven) ----------------
#define NX4  1048576
#define NW4  262144
#define NK4  65536
#define O1 (NX4)
#define O2 (O1 + NW4)
#define O3 (O2 + NK4)
#define O4 (O3 + NK4)
#define OT (O4 + NW4)

__global__ __launch_bounds__(256) void conv_all(
    const float* __restrict__ x, const float* __restrict__ wq, const float* __restrict__ wk,
    const float* __restrict__ wv, const float* __restrict__ wo,
    unsigned short* __restrict__ xb, unsigned short* __restrict__ wqkvb,
    unsigned short* __restrict__ wob) {
  int i = blockIdx.x * blockDim.x + threadIdx.x;
  const int stride = gridDim.x * blockDim.x;
  for (; i < OT; i += stride) {
    const float* src;
    unsigned short* dst;
    int j;
    if (i < O1)      { src = x;  dst = xb;                    j = i; }
    else if (i < O2) { src = wq; dst = wqkvb;                 j = i - O1; }
    else if (i < O3) { src = wk; dst = wqkvb + 1024 * 1024;   j = i - O2; }
    else if (i < O4) { src = wv; dst = wqkvb + 1280 * 1024;   j = i - O3; }
    else             { src = wo; dst = wob;                   j = i - O4; }
    const float4 v = reinterpret_cast<const float4*>(src)[j];
    ushort4 o;
    o.x = f2bf(v.x); o.y = f2bf(v.y); o.z = f2bf(v.z); o.w = f2bf(v.w);
    reinterpret_cast<ushort4*>(dst)[j] = o;
  }
}

// ------- fused QKV GEMM + rotary/rmsnorm/gate epilogue -------
// B-operand (weights, L2-resident) loaded DIRECT to registers (no LDS round trip;
// depth-1 named-reg prefetch, no WAR hazard so loads pipeline a full K-step ahead).
// A stays global_load_lds w16 into swizzled dbuf LDS (R17-proven). LDS reads/wave-step
// drop 12 -> 8; staging gloads 6 -> 4. K compile-time so the loop fully unrolls.
#define BK 64

__global__ __launch_bounds__(256) void gemm_qkv(
    const unsigned short* __restrict__ A, const unsigned short* __restrict__ Bw,
    const float* __restrict__ x, const float* __restrict__ ve,
    const float* __restrict__ cosb, const float* __restrict__ sinb,
    const float* __restrict__ Wg,
    unsigned short* __restrict__ Qn, unsigned short* __restrict__ Kn,
    unsigned short* __restrict__ Vt) {
  constexpr int BMT = 128, MI = 4, NI = 2, K = 1024;
  __shared__ char smem[50176];
  unsigned short* AlB = (unsigned short*)smem;             // 2 x [128*64]
  const int tid = threadIdx.x;
  const int lane = tid & 63;
  const int wid = tid >> 6;
  const int r = lane & 15, g = lane >> 4;
  const int wm = (wid >> 1) * 64, wn = (wid & 1) * 32;
  const int bm0 = blockIdx.y * BMT, bn0 = blockIdx.x * 64;
  const int lrow = lane >> 3;
  const int lcol = ((lane & 7) ^ lrow) * 8;
  const unsigned short* Asrc = A + (size_t)(bm0 + wid * 32 + lrow) * K + lcol;
  const unsigned short* BsrcD = Bw + (size_t)(bn0 + wn + r) * K + g * 8;  // direct B
  const int fsw = (r & 7) << 4;
  f32x4 acc[MI][NI] = {};

  auto stageA = [&](int k0, int buf) {
#pragma unroll
    for (int i = 0; i < 4; ++i)
      gload16(Asrc + (size_t)(i * 8) * K + k0, AlB + buf * 8192 + (wid * 32 + i * 8) * BK);
  };

  bf16x8 bcur[NI][2], bnxt[NI][2];
#define LOADB(DST, K0)                                                          \
  {                                                                             \
    _Pragma("unroll") for (int ni = 0; ni < NI; ++ni)                           \
    _Pragma("unroll") for (int s = 0; s < 2; ++s)                               \
      DST[ni][s] = *reinterpret_cast<const bf16x8*>(                            \
          BsrcD + (size_t)(ni * 16) * K + (K0) + s * 32);                       \
  }

  stageA(0, 0);
  LOADB(bcur, 0)
  __syncthreads();
  constexpr int nt = K / BK;
#pragma unroll
  for (int t = 0; t < nt; ++t) {
    const int cur = t & 1;
    if (t + 1 < nt) { stageA((t + 1) * BK, cur ^ 1); LOADB(bnxt, (t + 1) * BK) }
    const char* Ac = (const char*)(AlB + cur * 8192);
    bf16x8 af[MI][2];
#pragma unroll
    for (int mi = 0; mi < MI; ++mi)
#pragma unroll
      for (int s = 0; s < 2; ++s)
        af[mi][s] = *reinterpret_cast<const bf16x8*>(
            Ac + (wm + mi * 16 + r) * 128 + ((s * 64 + g * 16) ^ fsw));
#pragma unroll
    for (int s = 0; s < 2; ++s)
#pragma unroll
      for (int mi = 0; mi < MI; ++mi)
#pragma unroll
        for (int ni = 0; ni < NI; ++ni)
          acc[mi][ni] = __builtin_amdgcn_mfma_f32_16x16x32_bf16(af[mi][s], bcur[ni][s],
                                                                acc[mi][ni], 0, 0, 0);
    __syncthreads();
    if (t + 1 < nt) {
#pragma unroll
      for (int ni = 0; ni < NI; ++ni)
#pragma unroll
        for (int s = 0; s < 2; ++s) bcur[ni][s] = bnxt[ni][s];
    }
  }
  // ---- fused epilogue (R14-proven) ----
  float* Cl = (float*)smem;                                 // [128][65] f32
  unsigned short* Vst = (unsigned short*)(smem + 33280);    // [64][128] bf16
#pragma unroll
  for (int mi = 0; mi < MI; ++mi)
#pragma unroll
    for (int ni = 0; ni < NI; ++ni)
#pragma unroll
      for (int e = 0; e < 4; ++e)
        Cl[(wm + mi * 16 + g * 4 + e) * 65 + wn + ni * 16 + r] = acc[mi][ni][e];
  __syncthreads();
  const int head = blockIdx.x;
  const int trow = tid >> 1, half = tid & 1;
  const int tg = bm0 + trow;
  const int b = tg >> 11, t = tg & 2047;
  if (head < 20) {
    float r1[16], r2[16];
    float sq = 0.f;
#pragma unroll
    for (int i = 0; i < 16; ++i) {
      const int d = half * 16 + i;
      const float x1 = Cl[trow * 65 + d];
      const float x2 = Cl[trow * 65 + d + 32];
      const float c = cosb[t * 32 + d];
      const float s = sinb[t * 32 + d];
      r1[i] = x1 * c + x2 * s;
      r2[i] = x2 * c - x1 * s;
      sq += r1[i] * r1[i] + r2[i] * r2[i];
    }
    sq += __shfl_xor(sq, 1);
    const float sc = rsqrtf(sq * (1.0f / 64.0f) + 1.1920929e-7f) *
                     ((head < 16) ? 0.21640425613334453f : 1.2f);
    unsigned short* dst = (head < 16)
        ? Qn + (((size_t)b * NH + head) * T_ + t) * HD
        : Kn + (((size_t)b * NKV + (head - 16)) * T_ + t) * HD;
#pragma unroll
    for (int i4 = 0; i4 < 4; ++i4) {
      ushort4 w1, w2;
      w1.x = f2bf(r1[i4 * 4 + 0] * sc); w1.y = f2bf(r1[i4 * 4 + 1] * sc);
      w1.z = f2bf(r1[i4 * 4 + 2] * sc); w1.w = f2bf(r1[i4 * 4 + 3] * sc);
      w2.x = f2bf(r2[i4 * 4 + 0] * sc); w2.y = f2bf(r2[i4 * 4 + 1] * sc);
      w2.z = f2bf(r2[i4 * 4 + 2] * sc); w2.w = f2bf(r2[i4 * 4 + 3] * sc);
      *reinterpret_cast<ushort4*>(dst + half * 16 + i4 * 4) = w1;
      *reinterpret_cast<ushort4*>(dst + half * 16 + 32 + i4 * 4) = w2;
    }
  } else {
    const int kv = head - 20;
    float dot = 0.f;
#pragma unroll
    for (int i = 0; i < 12; ++i) dot += x[(size_t)tg * C_ + i] * Wg[kv * 12 + i];
    const float gate = 3.0f / (1.0f + __expf(-dot));
    const float* vsrc = ve + (size_t)tg * (NKV * HD) + kv * HD;
#pragma unroll
    for (int i = 0; i < 32; ++i) {
      const int d = half * 32 + i;
      Vst[d * 128 + trow] = f2bf(Cl[trow * 65 + d] + gate * vsrc[d]);
    }
    __syncthreads();
    const int dd = tid >> 2, t0 = (tid & 3) * 32;
    unsigned short* vd = Vt + (((size_t)b * NKV + kv) * HD + dd) * T_ + (bm0 & 2047) + t0;
    const unsigned short* vs2 = Vst + dd * 128 + t0;
#pragma unroll
    for (int i = 0; i < 4; ++i)
      *reinterpret_cast<bf16x8*>(vd + i * 8) = *reinterpret_cast<const bf16x8*>(vs2 + i * 8);
  }
}

// ---------------- GEMM: C[M,N] = A[M,K] * B[N,K]^T  (gemm2) ----------
// Same direct-register B treatment; A via gload_lds dbuf (LDS halves to 32KB).
template <int BMT, int BNT, bool OUTBF, int K>
__global__ __launch_bounds__(256) void gemm_bt(const unsigned short* __restrict__ A,
                                               const unsigned short* __restrict__ Bw,
                                               void* __restrict__ Cv, int M, int N) {
  constexpr int MI = BMT / 32;
  constexpr int NI = BNT / 32;
  __shared__ unsigned short Al[2][BMT * BK];
  const int tid = threadIdx.x;
  const int lane = tid & 63;
  const int wid = tid >> 6;
  const int r = lane & 15, g = lane >> 4;
  const int wm = (wid >> 1) * (BMT / 2), wn = (wid & 1) * (BNT / 2);
  const int bm0 = blockIdx.y * BMT, bn0 = blockIdx.x * BNT;
  const int lrow = lane >> 3;
  const int lcol = ((lane & 7) ^ lrow) * 8;
  const unsigned short* Asrc = A + (size_t)(bm0 + wid * (BMT / 4) + lrow) * K + lcol;
  const unsigned short* BsrcD = Bw + (size_t)(bn0 + wn + r) * K + g * 8;
  const int fsw = (r & 7) << 4;
  f32x4 acc[MI][NI] = {};

  auto stageA = [&](int k0, int buf) {
#pragma unroll
    for (int i = 0; i < BMT / 32; ++i)
      gload16(Asrc + (size_t)(i * 8) * K + k0, Al[buf] + (wid * (BMT / 4) + i * 8) * BK);
  };

  bf16x8 bcur[NI][2], bnxt[NI][2];
#define LOADB2(DST, K0)                                                         \
  {                                                                             \
    _Pragma("unroll") for (int ni = 0; ni < NI; ++ni)                           \
    _Pragma("unroll") for (int s = 0; s < 2; ++s)                               \
      DST[ni][s] = *reinterpret_cast<const bf16x8*>(                            \
          BsrcD + (size_t)(ni * 16) * K + (K0) + s * 32);                       \
  }

  stageA(0, 0);
  LOADB2(bcur, 0)
  __syncthreads();
  constexpr int nt = K / BK;
#pragma unroll
  for (int t = 0; t < nt; ++t) {
    const int cur = t & 1;
    if (t + 1 < nt) { stageA((t + 1) * BK, cur ^ 1); LOADB2(bnxt, (t + 1) * BK) }
    const char* Ac = (const char*)Al[cur];
    bf16x8 af[MI][2];
#pragma unroll
    for (int mi = 0; mi < MI; ++mi)
#pragma unroll
      for (int s = 0; s < 2; ++s)
        af[mi][s] = *reinterpret_cast<const bf16x8*>(
            Ac + (wm + mi * 16 + r) * 128 + ((s * 64 + g * 16) ^ fsw));
#pragma unroll
    for (int s = 0; s < 2; ++s)
#pragma unroll
      for (int mi = 0; mi < MI; ++mi)
#pragma unroll
        for (int ni = 0; ni < NI; ++ni)
          acc[mi][ni] = __builtin_amdgcn_mfma_f32_16x16x32_bf16(af[mi][s], bcur[ni][s],
                                                                acc[mi][ni], 0, 0, 0);
    __syncthreads();
    if (t + 1 < nt) {
#pragma unroll
      for (int ni = 0; ni < NI; ++ni)
#pragma unroll
        for (int s = 0; s < 2; ++s) bcur[ni][s] = bnxt[ni][s];
    }
  }
#pragma unroll
  for (int mi = 0; mi < MI; ++mi)
#pragma unroll
    for (int ni = 0; ni < NI; ++ni) {
      const int row = bm0 + wm + mi * 16 + g * 4;
      const int col = bn0 + wn + ni * 16 + r;
#pragma unroll
      for (int e = 0; e < 4; ++e) {
        if (OUTBF)
          ((unsigned short*)Cv)[(size_t)(row + e) * N + col] = f2bf(acc[mi][ni][e]);
        else
          ((float*)Cv)[(size_t)(row + e) * N + col] = acc[mi][ni][e];
      }
    }
}

// ---------------- flash attention, sliding window, GQA (R20, byte-identical) ----
__global__ __launch_bounds__(256, 4) void attn_fwd(
    const unsigned short* __restrict__ Qn, const unsigned short* __restrict__ Kn,
    const unsigned short* __restrict__ Vt, unsigned short* __restrict__ Y,
    const int* __restrict__ wlp) {
  __shared__ unsigned short Kl[2][KVB * 64];
  __shared__ unsigned short Vl[2][64 * KVB];
  __shared__ unsigned short Pl[4][16 * 64];
  const int flat = blockIdx.x;
  const int kvh = flat & 3, b = (flat >> 2) & 1;   // xcd group = flat & 7
  const int slot = flat >> 3;                       // 0..95
  const int h = kvh * 4 + (slot & 3);
  const int j = slot >> 2;                          // 0..23 equal-work index
  const int tid = threadIdx.x;
  const int wid = tid >> 6, lane = tid & 63;
  const int r = lane & 15, g = lane >> 4;
  const int wl = *wlp;
  const unsigned short* Kb = Kn + (size_t)(b * NKV + kvh) * T_ * HD;
  const unsigned short* Vb = Vt + (size_t)(b * NKV + kvh) * HD * T_;
  const int lrow = lane >> 3;
  const int lcol = ((lane & 7) ^ lrow) * 8;
  const unsigned short* KsrcG = Kb + (size_t)(wid * 16 + lrow) * HD + lcol;
  const unsigned short* VsrcG = Vb + (size_t)(wid * 16 + lrow) * T_ + lcol;
  char* Pwb = (char*)Pl[wid];
  const int swz = (r & 7) << 4;
  const int ksw = swz;
  const int nseg = (j < 8) ? 2 : 1;

  for (int seg = 0; seg < nseg; ++seg) {
    const int qt = (j < 8) ? (seg ? 15 - j : j) : j + 8;
    const int q0 = qt * 64;
    const int qs = q0 + wid * 16;
    const int q = qs + r;
    const unsigned short* Qb = Qn + ((size_t)(b * NH + h) * T_ + qs) * HD;
    const bf16x8 qf0 = *reinterpret_cast<const bf16x8*>(Qb + r * HD + g * 8);
    const bf16x8 qf1 = *reinterpret_cast<const bf16x8*>(Qb + r * HD + 32 + g * 8);
    float lrun = 0.f;
    f32x4 o[4] = {};
    int slo = q0 - wl; if (slo < 0) slo = 0;
    slo &= ~63;
    const int send = q0 + 63;

    auto stageKV = [&](int sb, int buf) {
#pragma unroll
      for (int i = 0; i < 2; ++i) {
        gload16(KsrcG + (size_t)(sb + i * 8) * HD,
                (unsigned short*)Kl[buf] + (wid * 16 + i * 8) * 64);
        gload16(VsrcG + (size_t)(i * 8) * T_ + sb,
                (unsigned short*)Vl[buf] + (wid * 16 + i * 8) * 64);
      }
    };

    stageKV(slo, 0);
    __syncthreads();

    int cur = 0;
    for (int sb = slo; sb <= send; sb += KVB) {
      const bool has_next = (sb + KVB <= send);
      if (has_next) stageKV(sb + KVB, cur ^ 1);
      {
        const char* Kc = (const char*)Kl[cur];
        const char* Vc = (const char*)Vl[cur];
        float sv[16];
        __builtin_amdgcn_s_setprio(1);
#pragma unroll
        for (int sub = 0; sub < 4; ++sub) {
          const int rowb = (sub * 16 + r) * 128;
          bf16x8 kf0 = *reinterpret_cast<const bf16x8*>(Kc + rowb + ((g * 16) ^ ksw));
          bf16x8 kf1 = *reinterpret_cast<const bf16x8*>(Kc + rowb + ((64 + g * 16) ^ ksw));
          f32x4 z = {};
          z = __builtin_amdgcn_mfma_f32_16x16x32_bf16(kf0, qf0, z, 0, 0, 0);
          z = __builtin_amdgcn_mfma_f32_16x16x32_bf16(kf1, qf1, z, 0, 0, 0);
#pragma unroll
          for (int e = 0; e < 4; ++e) sv[sub * 4 + e] = z[e];
        }
        __builtin_amdgcn_s_setprio(0);
        if (sb + 63 > qs || sb < qs + 15 - wl) {
#pragma unroll
          for (int i = 0; i < 16; ++i) {
            const int s_ = sb + (i >> 2) * 16 + g * 4 + (i & 3);
            const bool ok = (unsigned)(q - s_) <= (unsigned)wl;
            sv[i] = ok ? sv[i] : -__builtin_inff();
          }
        }
        float pe[16];
        float ps = 0.f;
#pragma unroll
        for (int i = 0; i < 16; ++i) {
          pe[i] = __builtin_amdgcn_exp2f(sv[i] - 17.0f);
          ps += pe[i];
        }
        lrun += ps;
#pragma unroll
        for (int sub = 0; sub < 4; ++sub) {
          unsigned w2[2];
          w2[0] = cvtpk(pe[sub * 4 + 0], pe[sub * 4 + 1]);
          w2[1] = cvtpk(pe[sub * 4 + 2], pe[sub * 4 + 3]);
          bf16x4 w;
          __builtin_memcpy(&w, w2, 8);
          *reinterpret_cast<bf16x4*>(Pwb + ((r * 128 + sub * 32 + g * 8) ^ swz)) = w;
        }
        asm volatile("s_waitcnt lgkmcnt(0)" ::: "memory");
        __builtin_amdgcn_s_setprio(1);
#pragma unroll
        for (int c = 0; c < 2; ++c) {
          const bf16x8 pf = *reinterpret_cast<const bf16x8*>(Pwb + ((r * 128 + c * 64 + g * 16) ^ swz));
#pragma unroll
          for (int dt = 0; dt < 4; ++dt) {
            const int vrow = (dt * 16 + r) * 128;
            const bf16x8 vf = *reinterpret_cast<const bf16x8*>(Vc + vrow + ((c * 64 + g * 16) ^ ksw));
            o[dt] = __builtin_amdgcn_mfma_f32_16x16x32_bf16(vf, pf, o[dt], 0, 0, 0);
          }
        }
        __builtin_amdgcn_s_setprio(0);
      }
      __syncthreads();
      cur ^= 1;
    }
    lrun += __shfl_xor(lrun, 16);
    lrun += __shfl_xor(lrun, 32);
    const float inv = 1.0f / lrun;
    unsigned short* Yb = Y + ((size_t)(b * T_) + qs + r) * (NH * HD) + h * HD;
#pragma unroll
    for (int dt = 0; dt < 4; ++dt)
#pragma unroll
      for (int e = 0; e < 4; ++e)
        Yb[dt * 16 + g * 4 + e] = f2bf(o[dt][e] * inv);
  }
}

extern "C" void kernel_launch(void* const* d_in, const int* in_sizes, int n_in,
                              void* d_out, int out_size, void* d_ws, size_t ws_size,
                              hipStream_t stream) {
  const float* x    = (const float*)d_in[0];
  const float* ve   = (const float*)d_in[1];
  const float* cosb = (const float*)d_in[2];
  const float* sinb = (const float*)d_in[3];
  const float* Wq   = (const float*)d_in[4];
  const float* Wk   = (const float*)d_in[5];
  const float* Wv   = (const float*)d_in[6];
  const float* Wo   = (const float*)d_in[7];
  const float* Wg   = (const float*)d_in[8];
  const int*   wlp  = (const int*)d_in[9];

  char* ws = (char*)d_ws;
  unsigned short* xb    = (unsigned short*)ws; ws += (size_t)4096 * 1024 * 2;
  unsigned short* wqkvb = (unsigned short*)ws; ws += (size_t)1536 * 1024 * 2;
  unsigned short* wob   = (unsigned short*)ws; ws += (size_t)1024 * 1024 * 2;
  unsigned short* Qn    = (unsigned short*)ws; ws += (size_t)B_ * NH * T_ * HD * 2;
  unsigned short* Kn    = (unsigned short*)ws; ws += (size_t)B_ * NKV * T_ * HD * 2;
  unsigned short* Vt    = (unsigned short*)ws; ws += (size_t)B_ * NKV * HD * T_ * 2;
  unsigned short* yb    = (unsigned short*)ws; ws += (size_t)4096 * 1024 * 2;

  conv_all<<<dim3(2048), dim3(256), 0, stream>>>(x, Wq, Wk, Wv, Wo, xb, wqkvb, wob);

  gemm_qkv<<<dim3(NQKV / 64, 4096 / 128), dim3(256), 0, stream>>>(
      xb, wqkvb, x, ve, cosb, sinb, Wg, Qn, Kn, Vt);

  attn_fwd<<<dim3(768), dim3(256), 0, stream>>>(Qn, Kn, Vt, yb, wlp);

  gemm_bt<128, 64, false, 1024><<<dim3(1024 / 64, 4096 / 128), dim3(256), 0, stream>>>(
      yb, wob, d_out, 4096, 1024);
}

// Round 22
// 76.005 us; speedup vs baseline: 1.2310x; 1.2310x over previous
//
#include <hip/hip_runtime.h>
#include <hip/hip_bf16.h>

#define B_ 2
#define T_ 2048
#define C_ 1024
#define NH 16
#define NKV 4
#define HD 64
#define NQKV 1536
#define KVB 64

typedef __attribute__((ext_vector_type(4))) float f32x4;
typedef __attribute__((ext_vector_type(8))) short bf16x8;
typedef __attribute__((ext_vector_type(4))) short bf16x4;

__device__ __forceinline__ unsigned short f2bf(float f) {
  __hip_bfloat16 h = __float2bfloat16(f);
  unsigned short u;
  __builtin_memcpy(&u, &h, 2);
  return u;
}

__device__ __forceinline__ void gload16(const void* g, void* l) {
  __builtin_amdgcn_global_load_lds(
      (const __attribute__((address_space(1))) void*)g,
      (__attribute__((address_space(3))) void*)l, 16, 0, 0);
}

__device__ __forceinline__ unsigned cvtpk(float lo, float hi_) {
  unsigned w;
  asm("v_cvt_pk_bf16_f32 %0, %1, %2" : "=v"(w) : "v"(lo), "v"(hi_));
  return w;
}

// ---------------- fused f32 -> bf16 convert for all 5 tensors (R17-proven) ----------------
#define NX4  1048576
#define NW4  262144
#define NK4  65536
#define O1 (NX4)
#define O2 (O1 + NW4)
#define O3 (O2 + NK4)
#define O4 (O3 + NK4)
#define OT (O4 + NW4)

__global__ __launch_bounds__(256) void conv_all(
    const float* __restrict__ x, const float* __restrict__ wq, const float* __restrict__ wk,
    const float* __restrict__ wv, const float* __restrict__ wo,
    unsigned short* __restrict__ xb, unsigned short* __restrict__ wqkvb,
    unsigned short* __restrict__ wob) {
  int i = blockIdx.x * blockDim.x + threadIdx.x;
  const int stride = gridDim.x * blockDim.x;
  for (; i < OT; i += stride) {
    const float* src;
    unsigned short* dst;
    int j;
    if (i < O1)      { src = x;  dst = xb;                    j = i; }
    else if (i < O2) { src = wq; dst = wqkvb;                 j = i - O1; }
    else if (i < O3) { src = wk; dst = wqkvb + 1024 * 1024;   j = i - O2; }
    else if (i < O4) { src = wv; dst = wqkvb + 1280 * 1024;   j = i - O3; }
    else             { src = wo; dst = wob;                   j = i - O4; }
    const float4 v = reinterpret_cast<const float4*>(src)[j];
    ushort4 o;
    o.x = f2bf(v.x); o.y = f2bf(v.y); o.z = f2bf(v.z); o.w = f2bf(v.w);
    reinterpret_cast<ushort4*>(dst)[j] = o;
  }
}

// ------- fused QKV GEMM + rotary/rmsnorm/gate epilogue (R14/R17/R20-proven) -------
#define BK 64

__global__ __launch_bounds__(256) void gemm_qkv(
    const unsigned short* __restrict__ A, const unsigned short* __restrict__ Bw,
    const float* __restrict__ x, const float* __restrict__ ve,
    const float* __restrict__ cosb, const float* __restrict__ sinb,
    const float* __restrict__ Wg,
    unsigned short* __restrict__ Qn, unsigned short* __restrict__ Kn,
    unsigned short* __restrict__ Vt) {
  constexpr int BMT = 128, MI = 4, NI = 2, K = 1024;
  __shared__ char smem[50176];
  unsigned short* AlB = (unsigned short*)smem;             // 2 x [128*64]
  unsigned short* BlB = (unsigned short*)(smem + 32768);   // 2 x [64*64]
  const int tid = threadIdx.x;
  const int lane = tid & 63;
  const int wid = tid >> 6;
  const int r = lane & 15, g = lane >> 4;
  const int wm = (wid >> 1) * 64, wn = (wid & 1) * 32;
  const int bm0 = blockIdx.y * BMT, bn0 = blockIdx.x * 64;
  const int lrow = lane >> 3;
  const int lcol = ((lane & 7) ^ lrow) * 8;
  const unsigned short* Asrc = A + (size_t)(bm0 + wid * 32 + lrow) * K + lcol;
  const unsigned short* Bsrc = Bw + (size_t)(bn0 + wid * 16 + lrow) * K + lcol;
  const int fsw = (r & 7) << 4;
  f32x4 acc[MI][NI] = {};

  auto stage = [&](int k0, int buf) {
#pragma unroll
    for (int i = 0; i < 4; ++i)
      gload16(Asrc + (size_t)(i * 8) * K + k0, AlB + buf * 8192 + (wid * 32 + i * 8) * BK);
#pragma unroll
    for (int i = 0; i < 2; ++i)
      gload16(Bsrc + (size_t)(i * 8) * K + k0, BlB + buf * 4096 + (wid * 16 + i * 8) * BK);
  };

  stage(0, 0);
  __syncthreads();
  const int nt = K / BK;
  for (int t = 0; t < nt; ++t) {
    const int cur = t & 1;
    if (t + 1 < nt) stage((t + 1) * BK, cur ^ 1);
    const char* Ac = (const char*)(AlB + cur * 8192);
    const char* Bc = (const char*)(BlB + cur * 4096);
    bf16x8 af[MI][2], bfr[NI][2];
#pragma unroll
    for (int mi = 0; mi < MI; ++mi)
#pragma unroll
      for (int s = 0; s < 2; ++s)
        af[mi][s] = *reinterpret_cast<const bf16x8*>(
            Ac + (wm + mi * 16 + r) * 128 + ((s * 64 + g * 16) ^ fsw));
#pragma unroll
    for (int ni = 0; ni < NI; ++ni)
#pragma unroll
      for (int s = 0; s < 2; ++s)
        bfr[ni][s] = *reinterpret_cast<const bf16x8*>(
            Bc + (wn + ni * 16 + r) * 128 + ((s * 64 + g * 16) ^ fsw));
#pragma unroll
    for (int s = 0; s < 2; ++s)
#pragma unroll
      for (int mi = 0; mi < MI; ++mi)
#pragma unroll
        for (int ni = 0; ni < NI; ++ni)
          acc[mi][ni] = __builtin_amdgcn_mfma_f32_16x16x32_bf16(af[mi][s], bfr[ni][s],
                                                                acc[mi][ni], 0, 0, 0);
    __syncthreads();
  }
  // ---- fused epilogue ----
  float* Cl = (float*)smem;                                 // [128][65] f32
  unsigned short* Vst = (unsigned short*)(smem + 33280);    // [64][128] bf16
#pragma unroll
  for (int mi = 0; mi < MI; ++mi)
#pragma unroll
    for (int ni = 0; ni < NI; ++ni)
#pragma unroll
      for (int e = 0; e < 4; ++e)
        Cl[(wm + mi * 16 + g * 4 + e) * 65 + wn + ni * 16 + r] = acc[mi][ni][e];
  __syncthreads();
  const int head = blockIdx.x;
  const int trow = tid >> 1, half = tid & 1;
  const int tg = bm0 + trow;
  const int b = tg >> 11, t = tg & 2047;
  if (head < 20) {
    float r1[16], r2[16];
    float sq = 0.f;
#pragma unroll
    for (int i = 0; i < 16; ++i) {
      const int d = half * 16 + i;
      const float x1 = Cl[trow * 65 + d];
      const float x2 = Cl[trow * 65 + d + 32];
      const float c = cosb[t * 32 + d];
      const float s = sinb[t * 32 + d];
      r1[i] = x1 * c + x2 * s;
      r2[i] = x2 * c - x1 * s;
      sq += r1[i] * r1[i] + r2[i] * r2[i];
    }
    sq += __shfl_xor(sq, 1);
    const float sc = rsqrtf(sq * (1.0f / 64.0f) + 1.1920929e-7f) *
                     ((head < 16) ? 0.21640425613334453f : 1.2f);
    unsigned short* dst = (head < 16)
        ? Qn + (((size_t)b * NH + head) * T_ + t) * HD
        : Kn + (((size_t)b * NKV + (head - 16)) * T_ + t) * HD;
#pragma unroll
    for (int i4 = 0; i4 < 4; ++i4) {
      ushort4 w1, w2;
      w1.x = f2bf(r1[i4 * 4 + 0] * sc); w1.y = f2bf(r1[i4 * 4 + 1] * sc);
      w1.z = f2bf(r1[i4 * 4 + 2] * sc); w1.w = f2bf(r1[i4 * 4 + 3] * sc);
      w2.x = f2bf(r2[i4 * 4 + 0] * sc); w2.y = f2bf(r2[i4 * 4 + 1] * sc);
      w2.z = f2bf(r2[i4 * 4 + 2] * sc); w2.w = f2bf(r2[i4 * 4 + 3] * sc);
      *reinterpret_cast<ushort4*>(dst + half * 16 + i4 * 4) = w1;
      *reinterpret_cast<ushort4*>(dst + half * 16 + 32 + i4 * 4) = w2;
    }
  } else {
    const int kv = head - 20;
    float dot = 0.f;
#pragma unroll
    for (int i = 0; i < 12; ++i) dot += x[(size_t)tg * C_ + i] * Wg[kv * 12 + i];
    const float gate = 3.0f / (1.0f + __expf(-dot));
    const float* vsrc = ve + (size_t)tg * (NKV * HD) + kv * HD;
#pragma unroll
    for (int i = 0; i < 32; ++i) {
      const int d = half * 32 + i;
      Vst[d * 128 + trow] = f2bf(Cl[trow * 65 + d] + gate * vsrc[d]);
    }
    __syncthreads();
    const int dd = tid >> 2, t0 = (tid & 3) * 32;
    unsigned short* vd = Vt + (((size_t)b * NKV + kv) * HD + dd) * T_ + (bm0 & 2047) + t0;
    const unsigned short* vs2 = Vst + dd * 128 + t0;
#pragma unroll
    for (int i = 0; i < 4; ++i)
      *reinterpret_cast<bf16x8*>(vd + i * 8) = *reinterpret_cast<const bf16x8*>(vs2 + i * 8);
  }
}

// ---------------- GEMM: C[M,N] = A[M,K] * B[N,K]^T  (gemm2, R12/R20-proven) ----------
template <int BMT, int BNT, bool OUTBF>
__global__ __launch_bounds__(256) void gemm_bt(const unsigned short* __restrict__ A,
                                               const unsigned short* __restrict__ Bw,
                                               void* __restrict__ Cv, int M, int N, int K) {
  constexpr int MI = BMT / 32;
  constexpr int NI = BNT / 32;
  __shared__ unsigned short Al[2][BMT * BK];
  __shared__ unsigned short Bl[2][BNT * BK];
  const int tid = threadIdx.x;
  const int lane = tid & 63;
  const int wid = tid >> 6;
  const int r = lane & 15, g = lane >> 4;
  const int wm = (wid >> 1) * (BMT / 2), wn = (wid & 1) * (BNT / 2);
  const int bm0 = blockIdx.y * BMT, bn0 = blockIdx.x * BNT;
  const int lrow = lane >> 3;
  const int lcol = ((lane & 7) ^ lrow) * 8;
  const unsigned short* Asrc = A + (size_t)(bm0 + wid * (BMT / 4) + lrow) * K + lcol;
  const unsigned short* Bsrc = Bw + (size_t)(bn0 + wid * (BNT / 4) + lrow) * K + lcol;
  const int fsw = (r & 7) << 4;
  f32x4 acc[MI][NI] = {};

  auto stage = [&](int k0, int buf) {
#pragma unroll
    for (int i = 0; i < BMT / 32; ++i)
      gload16(Asrc + (size_t)(i * 8) * K + k0, Al[buf] + (wid * (BMT / 4) + i * 8) * BK);
#pragma unroll
    for (int i = 0; i < BNT / 32; ++i)
      gload16(Bsrc + (size_t)(i * 8) * K + k0, Bl[buf] + (wid * (BNT / 4) + i * 8) * BK);
  };

  stage(0, 0);
  __syncthreads();
  const int nt = K / BK;
  for (int t = 0; t < nt; ++t) {
    const int cur = t & 1;
    if (t + 1 < nt) stage((t + 1) * BK, cur ^ 1);
    const char* Ac = (const char*)Al[cur];
    const char* Bc = (const char*)Bl[cur];
    bf16x8 af[MI][2], bfr[NI][2];
#pragma unroll
    for (int mi = 0; mi < MI; ++mi)
#pragma unroll
      for (int s = 0; s < 2; ++s)
        af[mi][s] = *reinterpret_cast<const bf16x8*>(
            Ac + (wm + mi * 16 + r) * 128 + ((s * 64 + g * 16) ^ fsw));
#pragma unroll
    for (int ni = 0; ni < NI; ++ni)
#pragma unroll
      for (int s = 0; s < 2; ++s)
        bfr[ni][s] = *reinterpret_cast<const bf16x8*>(
            Bc + (wn + ni * 16 + r) * 128 + ((s * 64 + g * 16) ^ fsw));
#pragma unroll
    for (int s = 0; s < 2; ++s)
#pragma unroll
      for (int mi = 0; mi < MI; ++mi)
#pragma unroll
        for (int ni = 0; ni < NI; ++ni)
          acc[mi][ni] = __builtin_amdgcn_mfma_f32_16x16x32_bf16(af[mi][s], bfr[ni][s],
                                                                acc[mi][ni], 0, 0, 0);
    __syncthreads();
  }
#pragma unroll
  for (int mi = 0; mi < MI; ++mi)
#pragma unroll
    for (int ni = 0; ni < NI; ++ni) {
      const int row = bm0 + wm + mi * 16 + g * 4;
      const int col = bn0 + wn + ni * 16 + r;
#pragma unroll
      for (int e = 0; e < 4; ++e) {
        if (OUTBF)
          ((unsigned short*)Cv)[(size_t)(row + e) * N + col] = f2bf(acc[mi][ni][e]);
        else
          ((float*)Cv)[(size_t)(row + e) * N + col] = acc[mi][ni][e];
      }
    }
}

// ---------------- flash attention, sliding window, GQA (R20-proven, byte-identical) ----
__global__ __launch_bounds__(256, 4) void attn_fwd(
    const unsigned short* __restrict__ Qn, const unsigned short* __restrict__ Kn,
    const unsigned short* __restrict__ Vt, unsigned short* __restrict__ Y,
    const int* __restrict__ wlp) {
  __shared__ unsigned short Kl[2][KVB * 64];
  __shared__ unsigned short Vl[2][64 * KVB];
  __shared__ unsigned short Pl[4][16 * 64];
  const int flat = blockIdx.x;
  const int kvh = flat & 3, b = (flat >> 2) & 1;   // xcd group = flat & 7
  const int slot = flat >> 3;                       // 0..95
  const int h = kvh * 4 + (slot & 3);
  const int j = slot >> 2;                          // 0..23 equal-work index
  const int tid = threadIdx.x;
  const int wid = tid >> 6, lane = tid & 63;
  const int r = lane & 15, g = lane >> 4;
  const int wl = *wlp;
  const unsigned short* Kb = Kn + (size_t)(b * NKV + kvh) * T_ * HD;
  const unsigned short* Vb = Vt + (size_t)(b * NKV + kvh) * HD * T_;
  const int lrow = lane >> 3;
  const int lcol = ((lane & 7) ^ lrow) * 8;
  const unsigned short* KsrcG = Kb + (size_t)(wid * 16 + lrow) * HD + lcol;
  const unsigned short* VsrcG = Vb + (size_t)(wid * 16 + lrow) * T_ + lcol;
  char* Pwb = (char*)Pl[wid];
  const int swz = (r & 7) << 4;
  const int ksw = swz;
  const int nseg = (j < 8) ? 2 : 1;

  for (int seg = 0; seg < nseg; ++seg) {
    const int qt = (j < 8) ? (seg ? 15 - j : j) : j + 8;
    const int q0 = qt * 64;
    const int qs = q0 + wid * 16;
    const int q = qs + r;
    const unsigned short* Qb = Qn + ((size_t)(b * NH + h) * T_ + qs) * HD;
    const bf16x8 qf0 = *reinterpret_cast<const bf16x8*>(Qb + r * HD + g * 8);
    const bf16x8 qf1 = *reinterpret_cast<const bf16x8*>(Qb + r * HD + 32 + g * 8);
    float lrun = 0.f;
    f32x4 o[4] = {};
    int slo = q0 - wl; if (slo < 0) slo = 0;
    slo &= ~63;
    const int send = q0 + 63;

    auto stageKV = [&](int sb, int buf) {
#pragma unroll
      for (int i = 0; i < 2; ++i) {
        gload16(KsrcG + (size_t)(sb + i * 8) * HD,
                (unsigned short*)Kl[buf] + (wid * 16 + i * 8) * 64);
        gload16(VsrcG + (size_t)(i * 8) * T_ + sb,
                (unsigned short*)Vl[buf] + (wid * 16 + i * 8) * 64);
      }
    };

    stageKV(slo, 0);
    __syncthreads();

    int cur = 0;
    for (int sb = slo; sb <= send; sb += KVB) {
      const bool has_next = (sb + KVB <= send);
      if (has_next) stageKV(sb + KVB, cur ^ 1);
      {
        const char* Kc = (const char*)Kl[cur];
        const char* Vc = (const char*)Vl[cur];
        float sv[16];
        __builtin_amdgcn_s_setprio(1);
#pragma unroll
        for (int sub = 0; sub < 4; ++sub) {
          const int rowb = (sub * 16 + r) * 128;
          bf16x8 kf0 = *reinterpret_cast<const bf16x8*>(Kc + rowb + ((g * 16) ^ ksw));
          bf16x8 kf1 = *reinterpret_cast<const bf16x8*>(Kc + rowb + ((64 + g * 16) ^ ksw));
          f32x4 z = {};
          z = __builtin_amdgcn_mfma_f32_16x16x32_bf16(kf0, qf0, z, 0, 0, 0);
          z = __builtin_amdgcn_mfma_f32_16x16x32_bf16(kf1, qf1, z, 0, 0, 0);
#pragma unroll
          for (int e = 0; e < 4; ++e) sv[sub * 4 + e] = z[e];
        }
        __builtin_amdgcn_s_setprio(0);
        if (sb + 63 > qs || sb < qs + 15 - wl) {
#pragma unroll
          for (int i = 0; i < 16; ++i) {
            const int s_ = sb + (i >> 2) * 16 + g * 4 + (i & 3);
            const bool ok = (unsigned)(q - s_) <= (unsigned)wl;
            sv[i] = ok ? sv[i] : -__builtin_inff();
          }
        }
        float pe[16];
        float ps = 0.f;
#pragma unroll
        for (int i = 0; i < 16; ++i) {
          pe[i] = __builtin_amdgcn_exp2f(sv[i] - 17.0f);
          ps += pe[i];
        }
        lrun += ps;
#pragma unroll
        for (int sub = 0; sub < 4; ++sub) {
          unsigned w2[2];
          w2[0] = cvtpk(pe[sub * 4 + 0], pe[sub * 4 + 1]);
          w2[1] = cvtpk(pe[sub * 4 + 2], pe[sub * 4 + 3]);
          bf16x4 w;
          __builtin_memcpy(&w, w2, 8);
          *reinterpret_cast<bf16x4*>(Pwb + ((r * 128 + sub * 32 + g * 8) ^ swz)) = w;
        }
        asm volatile("s_waitcnt lgkmcnt(0)" ::: "memory");
        __builtin_amdgcn_s_setprio(1);
#pragma unroll
        for (int c = 0; c < 2; ++c) {
          const bf16x8 pf = *reinterpret_cast<const bf16x8*>(Pwb + ((r * 128 + c * 64 + g * 16) ^ swz));
#pragma unroll
          for (int dt = 0; dt < 4; ++dt) {
            const int vrow = (dt * 16 + r) * 128;
            const bf16x8 vf = *reinterpret_cast<const bf16x8*>(Vc + vrow + ((c * 64 + g * 16) ^ ksw));
            o[dt] = __builtin_amdgcn_mfma_f32_16x16x32_bf16(vf, pf, o[dt], 0, 0, 0);
          }
        }
        __builtin_amdgcn_s_setprio(0);
      }
      __syncthreads();
      cur ^= 1;
    }
    lrun += __shfl_xor(lrun, 16);
    lrun += __shfl_xor(lrun, 32);
    const float inv = 1.0f / lrun;
    unsigned short* Yb = Y + ((size_t)(b * T_) + qs + r) * (NH * HD) + h * HD;
#pragma unroll
    for (int dt = 0; dt < 4; ++dt)
#pragma unroll
      for (int e = 0; e < 4; ++e)
        Yb[dt * 16 + g * 4 + e] = f2bf(o[dt][e] * inv);
  }
}

extern "C" void kernel_launch(void* const* d_in, const int* in_sizes, int n_in,
                              void* d_out, int out_size, void* d_ws, size_t ws_size,
                              hipStream_t stream) {
  const float* x    = (const float*)d_in[0];
  const float* ve   = (const float*)d_in[1];
  const float* cosb = (const float*)d_in[2];
  const float* sinb = (const float*)d_in[3];
  const float* Wq   = (const float*)d_in[4];
  const float* Wk   = (const float*)d_in[5];
  const float* Wv   = (const float*)d_in[6];
  const float* Wo   = (const float*)d_in[7];
  const float* Wg   = (const float*)d_in[8];
  const int*   wlp  = (const int*)d_in[9];

  char* ws = (char*)d_ws;
  unsigned short* xb    = (unsigned short*)ws; ws += (size_t)4096 * 1024 * 2;
  unsigned short* wqkvb = (unsigned short*)ws; ws += (size_t)1536 * 1024 * 2;
  unsigned short* wob   = (unsigned short*)ws; ws += (size_t)1024 * 1024 * 2;
  unsigned short* Qn    = (unsigned short*)ws; ws += (size_t)B_ * NH * T_ * HD * 2;
  unsigned short* Kn    = (unsigned short*)ws; ws += (size_t)B_ * NKV * T_ * HD * 2;
  unsigned short* Vt    = (unsigned short*)ws; ws += (size_t)B_ * NKV * HD * T_ * 2;
  unsigned short* yb    = (unsigned short*)ws; ws += (size_t)4096 * 1024 * 2;

  conv_all<<<dim3(2048), dim3(256), 0, stream>>>(x, Wq, Wk, Wv, Wo, xb, wqkvb, wob);

  gemm_qkv<<<dim3(NQKV / 64, 4096 / 128), dim3(256), 0, stream>>>(
      xb, wqkvb, x, ve, cosb, sinb, Wg, Qn, Kn, Vt);

  attn_fwd<<<dim3(768), dim3(256), 0, stream>>>(Qn, Kn, Vt, yb, wlp);

  gemm_bt<128, 64, false><<<dim3(1024 / 64, 4096 / 128), dim3(256), 0, stream>>>(
      yb, wob, d_out, 4096, 1024, 1024);
}

// Round 23
// 75.661 us; speedup vs baseline: 1.2366x; 1.0045x over previous
//
#include <hip/hip_runtime.h>
#include <hip/hip_bf16.h>

#define B_ 2
#define T_ 2048
#define C_ 1024
#define NH 16
#define NKV 4
#define HD 64
#define NQKV 1536
#define KVB 64

typedef __attribute__((ext_vector_type(4))) float f32x4;
typedef __attribute__((ext_vector_type(8))) short bf16x8;
typedef __attribute__((ext_vector_type(4))) short bf16x4;

__device__ __forceinline__ unsigned short f2bf(float f) {
  __hip_bfloat16 h = __float2bfloat16(f);
  unsigned short u;
  __builtin_memcpy(&u, &h, 2);
  return u;
}

__device__ __forceinline__ void gload16(const void* g, void* l) {
  __builtin_amdgcn_global_load_lds(
      (const __attribute__((address_space(1))) void*)g,
      (__attribute__((address_space(3))) void*)l, 16, 0, 0);
}

__device__ __forceinline__ unsigned cvtpk(float lo, float hi_) {
  unsigned w;
  asm("v_cvt_pk_bf16_f32 %0, %1, %2" : "=v"(w) : "v"(lo), "v"(hi_));
  return w;
}

// ---------------- fused f32 -> bf16 convert, 8 elems/thread ----------------
#define NX8  524288
#define NW8  131072
#define NK8  32768
#define P1 (NX8)
#define P2 (P1 + NW8)
#define P3 (P2 + NK8)
#define P4 (P3 + NK8)
#define PT (P4 + NW8)

__global__ __launch_bounds__(256) void conv_all(
    const float* __restrict__ x, const float* __restrict__ wq, const float* __restrict__ wk,
    const float* __restrict__ wv, const float* __restrict__ wo,
    unsigned short* __restrict__ xb, unsigned short* __restrict__ wqkvb,
    unsigned short* __restrict__ wob) {
  int i = blockIdx.x * blockDim.x + threadIdx.x;
  const int stride = gridDim.x * blockDim.x;
  for (; i < PT; i += stride) {
    const float* src;
    unsigned short* dst;
    int j;
    if (i < P1)      { src = x;  dst = xb;                    j = i; }
    else if (i < P2) { src = wq; dst = wqkvb;                 j = i - P1; }
    else if (i < P3) { src = wk; dst = wqkvb + 1024 * 1024;   j = i - P2; }
    else if (i < P4) { src = wv; dst = wqkvb + 1280 * 1024;   j = i - P3; }
    else             { src = wo; dst = wob;                   j = i - P4; }
    const float4 v0 = reinterpret_cast<const float4*>(src)[2 * j];
    const float4 v1 = reinterpret_cast<const float4*>(src)[2 * j + 1];
    unsigned w[4];
    w[0] = cvtpk(v0.x, v0.y); w[1] = cvtpk(v0.z, v0.w);
    w[2] = cvtpk(v1.x, v1.y); w[3] = cvtpk(v1.z, v1.w);
    bf16x8 o; __builtin_memcpy(&o, w, 16);
    reinterpret_cast<bf16x8*>(dst)[j] = o;
  }
}

// ------- fused QKV GEMM + rotary/rmsnorm/gate epilogue (R14/R17/R20-proven) -------
#define BK 64

__global__ __launch_bounds__(256) void gemm_qkv(
    const unsigned short* __restrict__ A, const unsigned short* __restrict__ Bw,
    const float* __restrict__ x, const float* __restrict__ ve,
    const float* __restrict__ cosb, const float* __restrict__ sinb,
    const float* __restrict__ Wg,
    unsigned short* __restrict__ Qn, unsigned short* __restrict__ Kn,
    unsigned short* __restrict__ Vt) {
  constexpr int BMT = 128, MI = 4, NI = 2, K = 1024;
  __shared__ char smem[50176];
  unsigned short* AlB = (unsigned short*)smem;             // 2 x [128*64]
  unsigned short* BlB = (unsigned short*)(smem + 32768);   // 2 x [64*64]
  const int tid = threadIdx.x;
  const int lane = tid & 63;
  const int wid = tid >> 6;
  const int r = lane & 15, g = lane >> 4;
  const int wm = (wid >> 1) * 64, wn = (wid & 1) * 32;
  const int bm0 = blockIdx.y * BMT, bn0 = blockIdx.x * 64;
  const int lrow = lane >> 3;
  const int lcol = ((lane & 7) ^ lrow) * 8;
  const unsigned short* Asrc = A + (size_t)(bm0 + wid * 32 + lrow) * K + lcol;
  const unsigned short* Bsrc = Bw + (size_t)(bn0 + wid * 16 + lrow) * K + lcol;
  const int fsw = (r & 7) << 4;
  f32x4 acc[MI][NI] = {};

  auto stage = [&](int k0, int buf) {
#pragma unroll
    for (int i = 0; i < 4; ++i)
      gload16(Asrc + (size_t)(i * 8) * K + k0, AlB + buf * 8192 + (wid * 32 + i * 8) * BK);
#pragma unroll
    for (int i = 0; i < 2; ++i)
      gload16(Bsrc + (size_t)(i * 8) * K + k0, BlB + buf * 4096 + (wid * 16 + i * 8) * BK);
  };

  stage(0, 0);
  __syncthreads();
  const int nt = K / BK;
  for (int t = 0; t < nt; ++t) {
    const int cur = t & 1;
    if (t + 1 < nt) stage((t + 1) * BK, cur ^ 1);
    const char* Ac = (const char*)(AlB + cur * 8192);
    const char* Bc = (const char*)(BlB + cur * 4096);
    bf16x8 af[MI][2], bfr[NI][2];
#pragma unroll
    for (int mi = 0; mi < MI; ++mi)
#pragma unroll
      for (int s = 0; s < 2; ++s)
        af[mi][s] = *reinterpret_cast<const bf16x8*>(
            Ac + (wm + mi * 16 + r) * 128 + ((s * 64 + g * 16) ^ fsw));
#pragma unroll
    for (int ni = 0; ni < NI; ++ni)
#pragma unroll
      for (int s = 0; s < 2; ++s)
        bfr[ni][s] = *reinterpret_cast<const bf16x8*>(
            Bc + (wn + ni * 16 + r) * 128 + ((s * 64 + g * 16) ^ fsw));
#pragma unroll
    for (int s = 0; s < 2; ++s)
#pragma unroll
      for (int mi = 0; mi < MI; ++mi)
#pragma unroll
        for (int ni = 0; ni < NI; ++ni)
          acc[mi][ni] = __builtin_amdgcn_mfma_f32_16x16x32_bf16(af[mi][s], bfr[ni][s],
                                                                acc[mi][ni], 0, 0, 0);
    __syncthreads();
  }
  // ---- fused epilogue ----
  float* Cl = (float*)smem;                                 // [128][65] f32
  unsigned short* Vst = (unsigned short*)(smem + 33280);    // [64][128] bf16
#pragma unroll
  for (int mi = 0; mi < MI; ++mi)
#pragma unroll
    for (int ni = 0; ni < NI; ++ni)
#pragma unroll
      for (int e = 0; e < 4; ++e)
        Cl[(wm + mi * 16 + g * 4 + e) * 65 + wn + ni * 16 + r] = acc[mi][ni][e];
  __syncthreads();
  const int head = blockIdx.x;
  const int trow = tid >> 1, half = tid & 1;
  const int tg = bm0 + trow;
  const int b = tg >> 11, t = tg & 2047;
  if (head < 20) {
    float r1[16], r2[16];
    float sq = 0.f;
#pragma unroll
    for (int i = 0; i < 16; ++i) {
      const int d = half * 16 + i;
      const float x1 = Cl[trow * 65 + d];
      const float x2 = Cl[trow * 65 + d + 32];
      const float c = cosb[t * 32 + d];
      const float s = sinb[t * 32 + d];
      r1[i] = x1 * c + x2 * s;
      r2[i] = x2 * c - x1 * s;
      sq += r1[i] * r1[i] + r2[i] * r2[i];
    }
    sq += __shfl_xor(sq, 1);
    const float sc = rsqrtf(sq * (1.0f / 64.0f) + 1.1920929e-7f) *
                     ((head < 16) ? 0.21640425613334453f : 1.2f);
    unsigned short* dst = (head < 16)
        ? Qn + (((size_t)b * NH + head) * T_ + t) * HD
        : Kn + (((size_t)b * NKV + (head - 16)) * T_ + t) * HD;
#pragma unroll
    for (int i4 = 0; i4 < 4; ++i4) {
      ushort4 w1, w2;
      w1.x = f2bf(r1[i4 * 4 + 0] * sc); w1.y = f2bf(r1[i4 * 4 + 1] * sc);
      w1.z = f2bf(r1[i4 * 4 + 2] * sc); w1.w = f2bf(r1[i4 * 4 + 3] * sc);
      w2.x = f2bf(r2[i4 * 4 + 0] * sc); w2.y = f2bf(r2[i4 * 4 + 1] * sc);
      w2.z = f2bf(r2[i4 * 4 + 2] * sc); w2.w = f2bf(r2[i4 * 4 + 3] * sc);
      *reinterpret_cast<ushort4*>(dst + half * 16 + i4 * 4) = w1;
      *reinterpret_cast<ushort4*>(dst + half * 16 + 32 + i4 * 4) = w2;
    }
  } else {
    const int kv = head - 20;
    float dot = 0.f;
#pragma unroll
    for (int i = 0; i < 12; ++i) dot += x[(size_t)tg * C_ + i] * Wg[kv * 12 + i];
    const float gate = 3.0f / (1.0f + __expf(-dot));
    const float* vsrc = ve + (size_t)tg * (NKV * HD) + kv * HD;
#pragma unroll
    for (int i = 0; i < 32; ++i) {
      const int d = half * 32 + i;
      Vst[d * 128 + trow] = f2bf(Cl[trow * 65 + d] + gate * vsrc[d]);
    }
    __syncthreads();
    const int dd = tid >> 2, t0 = (tid & 3) * 32;
    unsigned short* vd = Vt + (((size_t)b * NKV + kv) * HD + dd) * T_ + (bm0 & 2047) + t0;
    const unsigned short* vs2 = Vst + dd * 128 + t0;
#pragma unroll
    for (int i = 0; i < 4; ++i)
      *reinterpret_cast<bf16x8*>(vd + i * 8) = *reinterpret_cast<const bf16x8*>(vs2 + i * 8);
  }
}

// ---------------- GEMM: C[M,N] = A[M,K] * B[N,K]^T  (gemm2, R12/R20-proven) ----------
template <int BMT, int BNT, bool OUTBF>
__global__ __launch_bounds__(256) void gemm_bt(const unsigned short* __restrict__ A,
                                               const unsigned short* __restrict__ Bw,
                                               void* __restrict__ Cv, int M, int N, int K) {
  constexpr int MI = BMT / 32;
  constexpr int NI = BNT / 32;
  __shared__ unsigned short Al[2][BMT * BK];
  __shared__ unsigned short Bl[2][BNT * BK];
  const int tid = threadIdx.x;
  const int lane = tid & 63;
  const int wid = tid >> 6;
  const int r = lane & 15, g = lane >> 4;
  const int wm = (wid >> 1) * (BMT / 2), wn = (wid & 1) * (BNT / 2);
  const int bm0 = blockIdx.y * BMT, bn0 = blockIdx.x * BNT;
  const int lrow = lane >> 3;
  const int lcol = ((lane & 7) ^ lrow) * 8;
  const unsigned short* Asrc = A + (size_t)(bm0 + wid * (BMT / 4) + lrow) * K + lcol;
  const unsigned short* Bsrc = Bw + (size_t)(bn0 + wid * (BNT / 4) + lrow) * K + lcol;
  const int fsw = (r & 7) << 4;
  f32x4 acc[MI][NI] = {};

  auto stage = [&](int k0, int buf) {
#pragma unroll
    for (int i = 0; i < BMT / 32; ++i)
      gload16(Asrc + (size_t)(i * 8) * K + k0, Al[buf] + (wid * (BMT / 4) + i * 8) * BK);
#pragma unroll
    for (int i = 0; i < BNT / 32; ++i)
      gload16(Bsrc + (size_t)(i * 8) * K + k0, Bl[buf] + (wid * (BNT / 4) + i * 8) * BK);
  };

  stage(0, 0);
  __syncthreads();
  const int nt = K / BK;
  for (int t = 0; t < nt; ++t) {
    const int cur = t & 1;
    if (t + 1 < nt) stage((t + 1) * BK, cur ^ 1);
    const char* Ac = (const char*)Al[cur];
    const char* Bc = (const char*)Bl[cur];
    bf16x8 af[MI][2], bfr[NI][2];
#pragma unroll
    for (int mi = 0; mi < MI; ++mi)
#pragma unroll
      for (int s = 0; s < 2; ++s)
        af[mi][s] = *reinterpret_cast<const bf16x8*>(
            Ac + (wm + mi * 16 + r) * 128 + ((s * 64 + g * 16) ^ fsw));
#pragma unroll
    for (int ni = 0; ni < NI; ++ni)
#pragma unroll
      for (int s = 0; s < 2; ++s)
        bfr[ni][s] = *reinterpret_cast<const bf16x8*>(
            Bc + (wn + ni * 16 + r) * 128 + ((s * 64 + g * 16) ^ fsw));
#pragma unroll
    for (int s = 0; s < 2; ++s)
#pragma unroll
      for (int mi = 0; mi < MI; ++mi)
#pragma unroll
        for (int ni = 0; ni < NI; ++ni)
          acc[mi][ni] = __builtin_amdgcn_mfma_f32_16x16x32_bf16(af[mi][s], bfr[ni][s],
                                                                acc[mi][ni], 0, 0, 0);
    __syncthreads();
  }
#pragma unroll
  for (int mi = 0; mi < MI; ++mi)
#pragma unroll
    for (int ni = 0; ni < NI; ++ni) {
      const int row = bm0 + wm + mi * 16 + g * 4;
      const int col = bn0 + wn + ni * 16 + r;
#pragma unroll
      for (int e = 0; e < 4; ++e) {
        if (OUTBF)
          ((unsigned short*)Cv)[(size_t)(row + e) * N + col] = f2bf(acc[mi][ni][e]);
        else
          ((float*)Cv)[(size_t)(row + e) * N + col] = acc[mi][ni][e];
      }
    }
}

// ---------------- flash attention, sliding window, GQA (R20-proven + packed Y store) ----
__global__ __launch_bounds__(256, 4) void attn_fwd(
    const unsigned short* __restrict__ Qn, const unsigned short* __restrict__ Kn,
    const unsigned short* __restrict__ Vt, unsigned short* __restrict__ Y,
    const int* __restrict__ wlp) {
  __shared__ unsigned short Kl[2][KVB * 64];
  __shared__ unsigned short Vl[2][64 * KVB];
  __shared__ unsigned short Pl[4][16 * 64];
  const int flat = blockIdx.x;
  const int kvh = flat & 3, b = (flat >> 2) & 1;   // xcd group = flat & 7
  const int slot = flat >> 3;                       // 0..95
  const int h = kvh * 4 + (slot & 3);
  const int j = slot >> 2;                          // 0..23 equal-work index
  const int tid = threadIdx.x;
  const int wid = tid >> 6, lane = tid & 63;
  const int r = lane & 15, g = lane >> 4;
  const int wl = *wlp;
  const unsigned short* Kb = Kn + (size_t)(b * NKV + kvh) * T_ * HD;
  const unsigned short* Vb = Vt + (size_t)(b * NKV + kvh) * HD * T_;
  const int lrow = lane >> 3;
  const int lcol = ((lane & 7) ^ lrow) * 8;
  const unsigned short* KsrcG = Kb + (size_t)(wid * 16 + lrow) * HD + lcol;
  const unsigned short* VsrcG = Vb + (size_t)(wid * 16 + lrow) * T_ + lcol;
  char* Pwb = (char*)Pl[wid];
  const int swz = (r & 7) << 4;
  const int ksw = swz;
  const int nseg = (j < 8) ? 2 : 1;

  for (int seg = 0; seg < nseg; ++seg) {
    const int qt = (j < 8) ? (seg ? 15 - j : j) : j + 8;
    const int q0 = qt * 64;
    const int qs = q0 + wid * 16;
    const int q = qs + r;
    const unsigned short* Qb = Qn + ((size_t)(b * NH + h) * T_ + qs) * HD;
    const bf16x8 qf0 = *reinterpret_cast<const bf16x8*>(Qb + r * HD + g * 8);
    const bf16x8 qf1 = *reinterpret_cast<const bf16x8*>(Qb + r * HD + 32 + g * 8);
    float lrun = 0.f;
    f32x4 o[4] = {};
    int slo = q0 - wl; if (slo < 0) slo = 0;
    slo &= ~63;
    const int send = q0 + 63;

    auto stageKV = [&](int sb, int buf) {
#pragma unroll
      for (int i = 0; i < 2; ++i) {
        gload16(KsrcG + (size_t)(sb + i * 8) * HD,
                (unsigned short*)Kl[buf] + (wid * 16 + i * 8) * 64);
        gload16(VsrcG + (size_t)(i * 8) * T_ + sb,
                (unsigned short*)Vl[buf] + (wid * 16 + i * 8) * 64);
      }
    };

    stageKV(slo, 0);
    __syncthreads();

    int cur = 0;
    for (int sb = slo; sb <= send; sb += KVB) {
      const bool has_next = (sb + KVB <= send);
      if (has_next) stageKV(sb + KVB, cur ^ 1);
      {
        const char* Kc = (const char*)Kl[cur];
        const char* Vc = (const char*)Vl[cur];
        float sv[16];
        __builtin_amdgcn_s_setprio(1);
#pragma unroll
        for (int sub = 0; sub < 4; ++sub) {
          const int rowb = (sub * 16 + r) * 128;
          bf16x8 kf0 = *reinterpret_cast<const bf16x8*>(Kc + rowb + ((g * 16) ^ ksw));
          bf16x8 kf1 = *reinterpret_cast<const bf16x8*>(Kc + rowb + ((64 + g * 16) ^ ksw));
          f32x4 z = {};
          z = __builtin_amdgcn_mfma_f32_16x16x32_bf16(kf0, qf0, z, 0, 0, 0);
          z = __builtin_amdgcn_mfma_f32_16x16x32_bf16(kf1, qf1, z, 0, 0, 0);
#pragma unroll
          for (int e = 0; e < 4; ++e) sv[sub * 4 + e] = z[e];
        }
        __builtin_amdgcn_s_setprio(0);
        if (sb + 63 > qs || sb < qs + 15 - wl) {
#pragma unroll
          for (int i = 0; i < 16; ++i) {
            const int s_ = sb + (i >> 2) * 16 + g * 4 + (i & 3);
            const bool ok = (unsigned)(q - s_) <= (unsigned)wl;
            sv[i] = ok ? sv[i] : -__builtin_inff();
          }
        }
        float pe[16];
        float ps = 0.f;
#pragma unroll
        for (int i = 0; i < 16; ++i) {
          pe[i] = __builtin_amdgcn_exp2f(sv[i] - 17.0f);
          ps += pe[i];
        }
        lrun += ps;
#pragma unroll
        for (int sub = 0; sub < 4; ++sub) {
          unsigned w2[2];
          w2[0] = cvtpk(pe[sub * 4 + 0], pe[sub * 4 + 1]);
          w2[1] = cvtpk(pe[sub * 4 + 2], pe[sub * 4 + 3]);
          bf16x4 w;
          __builtin_memcpy(&w, w2, 8);
          *reinterpret_cast<bf16x4*>(Pwb + ((r * 128 + sub * 32 + g * 8) ^ swz)) = w;
        }
        asm volatile("s_waitcnt lgkmcnt(0)" ::: "memory");
        __builtin_amdgcn_s_setprio(1);
#pragma unroll
        for (int c = 0; c < 2; ++c) {
          const bf16x8 pf = *reinterpret_cast<const bf16x8*>(Pwb + ((r * 128 + c * 64 + g * 16) ^ swz));
#pragma unroll
          for (int dt = 0; dt < 4; ++dt) {
            const int vrow = (dt * 16 + r) * 128;
            const bf16x8 vf = *reinterpret_cast<const bf16x8*>(Vc + vrow + ((c * 64 + g * 16) ^ ksw));
            o[dt] = __builtin_amdgcn_mfma_f32_16x16x32_bf16(vf, pf, o[dt], 0, 0, 0);
          }
        }
        __builtin_amdgcn_s_setprio(0);
      }
      __syncthreads();
      cur ^= 1;
    }
    lrun += __shfl_xor(lrun, 16);
    lrun += __shfl_xor(lrun, 32);
    const float inv = 1.0f / lrun;
    unsigned short* Yb = Y + ((size_t)(b * T_) + qs + r) * (NH * HD) + h * HD;
#pragma unroll
    for (int dt = 0; dt < 4; ++dt) {
      ushort4 w;
      w.x = f2bf(o[dt][0] * inv);
      w.y = f2bf(o[dt][1] * inv);
      w.z = f2bf(o[dt][2] * inv);
      w.w = f2bf(o[dt][3] * inv);
      *reinterpret_cast<ushort4*>(Yb + dt * 16 + g * 4) = w;
    }
  }
}

extern "C" void kernel_launch(void* const* d_in, const int* in_sizes, int n_in,
                              void* d_out, int out_size, void* d_ws, size_t ws_size,
                              hipStream_t stream) {
  const float* x    = (const float*)d_in[0];
  const float* ve   = (const float*)d_in[1];
  const float* cosb = (const float*)d_in[2];
  const float* sinb = (const float*)d_in[3];
  const float* Wq   = (const float*)d_in[4];
  const float* Wk   = (const float*)d_in[5];
  const float* Wv   = (const float*)d_in[6];
  const float* Wo   = (const float*)d_in[7];
  const float* Wg   = (const float*)d_in[8];
  const int*   wlp  = (const int*)d_in[9];

  char* ws = (char*)d_ws;
  unsigned short* xb    = (unsigned short*)ws; ws += (size_t)4096 * 1024 * 2;
  unsigned short* wqkvb = (unsigned short*)ws; ws += (size_t)1536 * 1024 * 2;
  unsigned short* wob   = (unsigned short*)ws; ws += (size_t)1024 * 1024 * 2;
  unsigned short* Qn    = (unsigned short*)ws; ws += (size_t)B_ * NH * T_ * HD * 2;
  unsigned short* Kn    = (unsigned short*)ws; ws += (size_t)B_ * NKV * T_ * HD * 2;
  unsigned short* Vt    = (unsigned short*)ws; ws += (size_t)B_ * NKV * HD * T_ * 2;
  unsigned short* yb    = (unsigned short*)ws; ws += (size_t)4096 * 1024 * 2;

  conv_all<<<dim3(2048), dim3(256), 0, stream>>>(x, Wq, Wk, Wv, Wo, xb, wqkvb, wob);

  gemm_qkv<<<dim3(NQKV / 64, 4096 / 128), dim3(256), 0, stream>>>(
      xb, wqkvb, x, ve, cosb, sinb, Wg, Qn, Kn, Vt);

  attn_fwd<<<dim3(768), dim3(256), 0, stream>>>(Qn, Kn, Vt, yb, wlp);

  gemm_bt<128, 64, false><<<dim3(1024 / 64, 4096 / 128), dim3(256), 0, stream>>>(
      yb, wob, d_out, 4096, 1024, 1024);
}